// Round 1
// baseline (4238.649 us; speedup 1.0000x reference)
//
#include <hip/hip_runtime.h>
#include <hip/hip_bf16.h>
#include <stdint.h>

// Problem constants: B=4, S=512, E=768, H=12, D=64, L=12, FF=3072, M = B*S = 2048
#define LAYERS 12
#define M_ROWS 2048
#define E_DIM 768
#define FF_DIM 3072
#define QKV_DIM 2304
#define SCALE_INV 0.036084391824351615f  // 1/sqrt(768)

typedef __hip_bfloat16 bf16;
typedef __attribute__((ext_vector_type(8))) __bf16 bf16x8;
typedef __attribute__((ext_vector_type(4))) float f32x4;

__device__ __forceinline__ float bf2f(bf16 v) { return __bfloat162float(v); }
__device__ __forceinline__ bf16 f2bf(float v) { return __float2bfloat16(v); }

__device__ __forceinline__ float gelu_f(float x) {
  return 0.5f * x * (1.0f + erff(x * 0.70710678118654752f));
}

// ---------------------------------------------------------------------------
// Batched weight transpose+convert: fp32 [K][N] -> bf16 [N][K] for the 4
// weight matrices of one layer. 32x32 tiles via LDS.
// tiles: W_qkv(768x2304)=1728, W_p(768x768)=576, W_1(768x3072)=2304,
//        W_2(3072x768)=2304  -> total 6912 blocks.
// ---------------------------------------------------------------------------
__global__ __launch_bounds__(256) void transpose_k(
    const float* __restrict__ w0, const float* __restrict__ w1,
    const float* __restrict__ w2, const float* __restrict__ w3,
    bf16* __restrict__ t0, bf16* __restrict__ t1,
    bf16* __restrict__ t2, bf16* __restrict__ t3)
{
  __shared__ float T[32][33];
  int bid = blockIdx.x;
  const float* src; bf16* dst; int K, N, tile;
  if (bid < 1728)      { src = w0; dst = t0; K = 768;  N = 2304; tile = bid; }
  else if (bid < 2304) { src = w1; dst = t1; K = 768;  N = 768;  tile = bid - 1728; }
  else if (bid < 4608) { src = w2; dst = t2; K = 768;  N = 3072; tile = bid - 2304; }
  else                 { src = w3; dst = t3; K = 3072; N = 768;  tile = bid - 4608; }
  int tilesN = N >> 5;
  int tk = tile / tilesN;
  int tn = tile - tk * tilesN;
  int tx = threadIdx.x & 31, ty = threadIdx.x >> 5;
  int k0 = tk << 5, n0 = tn << 5;
#pragma unroll
  for (int i = 0; i < 4; i++)
    T[ty + i * 8][tx] = src[(size_t)(k0 + ty + i * 8) * N + n0 + tx];
  __syncthreads();
#pragma unroll
  for (int i = 0; i < 4; i++)
    dst[(size_t)(n0 + ty + i * 8) * K + k0 + tx] = f2bf(T[tx][ty + i * 8]);
}

// ---------------------------------------------------------------------------
// LayerNorm over last dim (768). One block (256 thr) per row.
// out = LN(in)*gamma+beta [+ add0] [+ add1];  fp32 or bf16 output.
// NOTE: no __restrict__ here — add1 and outp may alias (in-place residual).
// ---------------------------------------------------------------------------
template<int OUT_BF16, int NADD>
__global__ __launch_bounds__(256) void ln_k(
    const float* in, const float* gamma, const float* beta,
    const float* add0, const float* add1, void* outp)
{
  int row = blockIdx.x, tid = threadIdx.x;
  const float* x = in + (size_t)row * 768;
  float v[3]; float s = 0.f, sq = 0.f;
#pragma unroll
  for (int j = 0; j < 3; j++) {
    v[j] = x[tid + j * 256];
    s += v[j]; sq += v[j] * v[j];
  }
#pragma unroll
  for (int off = 32; off; off >>= 1) {
    s += __shfl_xor(s, off);
    sq += __shfl_xor(sq, off);
  }
  __shared__ float red[8];
  int wv = tid >> 6;
  if ((tid & 63) == 0) { red[wv] = s; red[4 + wv] = sq; }
  __syncthreads();
  s  = red[0] + red[1] + red[2] + red[3];
  sq = red[4] + red[5] + red[6] + red[7];
  float mean = s * (1.0f / 768.0f);
  float var  = sq * (1.0f / 768.0f) - mean * mean;
  float rstd = rsqrtf(var + 1e-5f);
#pragma unroll
  for (int j = 0; j < 3; j++) {
    int c = tid + j * 256;
    float val = (v[j] - mean) * rstd * gamma[c] + beta[c];
    if (NADD >= 1) val += add0[(size_t)row * 768 + c];
    if (NADD >= 2) val += add1[(size_t)row * 768 + c];
    if (OUT_BF16) ((bf16*)outp)[(size_t)row * 768 + c] = f2bf(val);
    else          ((float*)outp)[(size_t)row * 768 + c] = val;
  }
}

// ---------------------------------------------------------------------------
// bf16 MFMA GEMM:  C[M=2048][N] = A[2048][K] @ W[K][N] + bias
// A: bf16 row-major [M][K].  BT: bf16 [N][K] (pre-transposed W).
// 64x64 tile per 256-thread block, 4 waves each doing 32x32 (2x2 mfma tiles).
// OUT_MODE: 0 = fp32 out, 1 = bf16 out, 2 = bf16+GELU out,
//           3 = split-QKV out (col = h*192 + d*3 + t; t in {q,k,v}),
//               writing q/k/v as [B][H][S][D] bf16.
// ---------------------------------------------------------------------------
template<int OUT_MODE>
__global__ __launch_bounds__(256) void gemm_k(
    const bf16* __restrict__ A, const bf16* __restrict__ BT,
    const float* __restrict__ bias, void* __restrict__ Cout,
    bf16* __restrict__ qo, bf16* __restrict__ ko, bf16* __restrict__ vo,
    int N, int K)
{
  __shared__ __align__(16) bf16 Als[64 * 32];
  __shared__ __align__(16) bf16 Bls[64 * 32];
  int tid = threadIdx.x;
  int lane = tid & 63, wave = tid >> 6;
  int wm = (wave >> 1) * 32, wn = (wave & 1) * 32;
  int m0 = (blockIdx.x & 31) << 6;
  int n0 = (blockIdx.x >> 5) << 6;
  const bf16* Ap = A + (size_t)m0 * K;
  const bf16* Bp = BT + (size_t)n0 * K;
  int sr = tid >> 2;            // staging row 0..63
  int sc = (tid & 3) * 8;       // staging col offset {0,8,16,24}
  f32x4 acc[2][2] = {};
  for (int k0 = 0; k0 < K; k0 += 32) {
    uint4 av = *(const uint4*)(Ap + (size_t)sr * K + k0 + sc);
    uint4 bv = *(const uint4*)(Bp + (size_t)sr * K + k0 + sc);
    __syncthreads();   // previous iter's LDS reads complete
    *(uint4*)&Als[tid * 8] = av;
    *(uint4*)&Bls[tid * 8] = bv;
    __syncthreads();
    int ko8 = (lane >> 4) * 8;
    bf16x8 af[2], bfr[2];
#pragma unroll
    for (int i = 0; i < 2; i++)
      af[i] = *(const bf16x8*)&Als[(wm + i * 16 + (lane & 15)) * 32 + ko8];
#pragma unroll
    for (int j = 0; j < 2; j++)
      bfr[j] = *(const bf16x8*)&Bls[(wn + j * 16 + (lane & 15)) * 32 + ko8];
#pragma unroll
    for (int i = 0; i < 2; i++)
#pragma unroll
      for (int j = 0; j < 2; j++)
        acc[i][j] = __builtin_amdgcn_mfma_f32_16x16x32_bf16(af[i], bfr[j], acc[i][j], 0, 0, 0);
  }
  // epilogue: C/D layout col = lane&15, row = (lane>>4)*4 + reg
#pragma unroll
  for (int i = 0; i < 2; i++) {
    int mbase = m0 + wm + i * 16 + ((lane >> 4) << 2);
#pragma unroll
    for (int j = 0; j < 2; j++) {
      int n = n0 + wn + j * 16 + (lane & 15);
      float bvs = bias[n];
      if (OUT_MODE == 3) {
        int h = n / 192;
        int rm = n - h * 192;
        int d = rm / 3;
        int t = rm - d * 3;
        bf16* dsts = (t == 0) ? qo : (t == 1) ? ko : vo;
#pragma unroll
        for (int rg = 0; rg < 4; rg++) {
          int m = mbase + rg;
          float val = acc[i][j][rg] + bvs;
          int b = m >> 9, sIdx = m & 511;
          dsts[(size_t)(((b * 12 + h) << 9) + sIdx) * 64 + d] = f2bf(val);
        }
      } else {
#pragma unroll
        for (int rg = 0; rg < 4; rg++) {
          int m = mbase + rg;
          float val = acc[i][j][rg] + bvs;
          if (OUT_MODE == 0)      ((float*)Cout)[(size_t)m * N + n] = val;
          else if (OUT_MODE == 1) ((bf16*)Cout)[(size_t)m * N + n] = f2bf(val);
          else                    ((bf16*)Cout)[(size_t)m * N + n] = f2bf(gelu_f(val));
        }
      }
    }
  }
}

// ---------------------------------------------------------------------------
// Attention: per block = one (b,h) pair and 4 query rows. S=512, D=64.
// q/k/v: bf16 [B][H][S][D].  o: bf16 [B*S][768] (col = h*64+d).
// att = softmax(q.k) / sqrt(768)   (scale applied AFTER softmax — faithful)
// ---------------------------------------------------------------------------
__global__ __launch_bounds__(256) void attn_k(
    const bf16* __restrict__ q, const bf16* __restrict__ k,
    const bf16* __restrict__ v, bf16* __restrict__ o)
{
  __shared__ float qs[4][64];
  __shared__ float e[4][512];
  __shared__ float red[8][4][64];
  int tid = threadIdx.x;
  int qt = blockIdx.x & 127;          // 128 query-tiles of 4
  int bh = blockIdx.x >> 7;           // 0..47
  size_t base = (size_t)bh * 32768;   // 512*64
  int s0 = qt * 4;
  {
    int qi = tid >> 6, d = tid & 63;
    qs[qi][d] = bf2f(q[base + (size_t)(s0 + qi) * 64 + d]);
  }
  __syncthreads();
  // energies: 2 keys per thread, dot over D=64 for 4 query rows
#pragma unroll
  for (int rep = 0; rep < 2; rep++) {
    int j = tid + rep * 256;
    const bf16* kr = k + base + (size_t)j * 64;
    float a0 = 0, a1 = 0, a2 = 0, a3 = 0;
#pragma unroll
    for (int c = 0; c < 64; c += 8) {
      uint4 u4 = *(const uint4*)(kr + c);
      unsigned us[4] = {u4.x, u4.y, u4.z, u4.w};
#pragma unroll
      for (int p = 0; p < 4; p++) {
        float lo = __uint_as_float(us[p] << 16);
        float hi = __uint_as_float(us[p] & 0xffff0000u);
        int d0 = c + p * 2;
        a0 += lo * qs[0][d0] + hi * qs[0][d0 + 1];
        a1 += lo * qs[1][d0] + hi * qs[1][d0 + 1];
        a2 += lo * qs[2][d0] + hi * qs[2][d0 + 1];
        a3 += lo * qs[3][d0] + hi * qs[3][d0 + 1];
      }
    }
    e[0][j] = a0; e[1][j] = a1; e[2][j] = a2; e[3][j] = a3;
  }
  __syncthreads();
  // softmax: wave w handles query row w (512 values, 8 per lane)
  {
    int w = tid >> 6, lane = tid & 63;
    float vals[8];
    float m = -1e30f;
#pragma unroll
    for (int t = 0; t < 8; t++) {
      vals[t] = e[w][lane + t * 64];
      m = fmaxf(m, vals[t]);
    }
#pragma unroll
    for (int off = 32; off; off >>= 1) m = fmaxf(m, __shfl_xor(m, off));
    float ssum = 0.f;
#pragma unroll
    for (int t = 0; t < 8; t++) { vals[t] = __expf(vals[t] - m); ssum += vals[t]; }
#pragma unroll
    for (int off = 32; off; off >>= 1) ssum += __shfl_xor(ssum, off);
    float inv = SCALE_INV / ssum;
#pragma unroll
    for (int t = 0; t < 8; t++) e[w][lane + t * 64] = vals[t] * inv;
  }
  __syncthreads();
  // PV: thread = (d-pair 0..31) x (key-group 0..7), 64 keys per group
  {
    int dp = tid & 31;
    int g8 = tid >> 5;
    const bf16* vbp = v + base;
    float acc[4][2] = {};
    for (int jj = 0; jj < 64; jj++) {
      int j = g8 * 64 + jj;
      unsigned u = *(const unsigned*)(vbp + (size_t)j * 64 + dp * 2);
      float lo = __uint_as_float(u << 16);
      float hi = __uint_as_float(u & 0xffff0000u);
#pragma unroll
      for (int qi = 0; qi < 4; qi++) {
        float p = e[qi][j];
        acc[qi][0] += p * lo;
        acc[qi][1] += p * hi;
      }
    }
#pragma unroll
    for (int qi = 0; qi < 4; qi++) {
      red[g8][qi][dp * 2]     = acc[qi][0];
      red[g8][qi][dp * 2 + 1] = acc[qi][1];
    }
  }
  __syncthreads();
  {
    int qi = tid >> 6, d = tid & 63;
    float sum = 0.f;
#pragma unroll
    for (int g = 0; g < 8; g++) sum += red[g][qi][d];
    int b = bh / 12, h = bh - b * 12;
    o[(size_t)(b * 512 + s0 + qi) * 768 + h * 64 + d] = f2bf(sum);
  }
}

// ---------------------------------------------------------------------------
extern "C" void kernel_launch(void* const* d_in, const int* in_sizes, int n_in,
                              void* d_out, int out_size, void* d_ws, size_t ws_size,
                              hipStream_t stream)
{
  const float* x    = (const float*)d_in[0];
  const float* Wqkv = (const float*)d_in[1];
  const float* bqkv = (const float*)d_in[2];
  const float* Wp   = (const float*)d_in[3];
  const float* bp   = (const float*)d_in[4];
  const float* W1   = (const float*)d_in[5];
  const float* b1   = (const float*)d_in[6];
  const float* W2   = (const float*)d_in[7];
  const float* b2   = (const float*)d_in[8];
  const float* g1  = (const float*)d_in[9];
  const float* be1 = (const float*)d_in[10];
  const float* g2  = (const float*)d_in[11];
  const float* be2 = (const float*)d_in[12];
  const float* g3  = (const float*)d_in[13];
  const float* be3 = (const float*)d_in[14];
  const float* g4  = (const float*)d_in[15];
  const float* be4 = (const float*)d_in[16];
  float* xout = (float*)d_out;

  char* ws = (char*)d_ws;
  size_t off = 0;
  auto alloc = [&](size_t bytes) -> char* {
    char* p = ws + off;
    off += (bytes + 255) & ~(size_t)255;
    return p;
  };
  const size_t NTOK = (size_t)M_ROWS * E_DIM;          // 1,572,864
  bf16*  qb  = (bf16*)alloc(NTOK * 2);
  bf16*  kb  = (bf16*)alloc(NTOK * 2);
  bf16*  vb  = (bf16*)alloc(NTOK * 2);
  bf16*  hb  = (bf16*)alloc(NTOK * 2);
  bf16*  ob  = (bf16*)alloc(NTOK * 2);
  bf16*  f1b = (bf16*)alloc((size_t)M_ROWS * FF_DIM * 2);
  float* tmp = (float*)alloc(NTOK * 4);
  float* r1  = (float*)alloc(NTOK * 4);
  bf16*  tq  = (bf16*)alloc((size_t)768 * 2304 * 2);
  bf16*  tp  = (bf16*)alloc((size_t)768 * 768 * 2);
  bf16*  t1  = (bf16*)alloc((size_t)768 * 3072 * 2);
  bf16*  t2  = (bf16*)alloc((size_t)3072 * 768 * 2);
  if (off > ws_size) {
    // workspace too small: emit an unmistakable sentinel instead of corrupting
    hipMemsetAsync(d_out, 0x7f, (size_t)out_size * 4, stream);
    return;
  }

  hipMemcpyAsync(d_out, x, (size_t)out_size * 4, hipMemcpyDeviceToDevice, stream);

  for (int l = 0; l < LAYERS; l++) {
    const float* wq  = Wqkv + (size_t)l * 768 * 2304;
    const float* wp_ = Wp   + (size_t)l * 768 * 768;
    const float* w1_ = W1   + (size_t)l * 768 * 3072;
    const float* w2_ = W2   + (size_t)l * 3072 * 768;

    transpose_k<<<6912, 256, 0, stream>>>(wq, wp_, w1_, w2_, tq, tp, t1, t2);

    // h = LN1(x)  -> bf16
    ln_k<1, 0><<<2048, 256, 0, stream>>>(xout, g1 + l * 768, be1 + l * 768,
                                         nullptr, nullptr, hb);
    // qkv = h @ Wqkv + bqkv, split into q/k/v [B][H][S][D]
    gemm_k<3><<<32 * 36, 256, 0, stream>>>(hb, tq, bqkv + (size_t)l * 2304,
                                           nullptr, qb, kb, vb, 2304, 768);
    // attention -> ob [B*S][768] bf16
    attn_k<<<6144, 256, 0, stream>>>(qb, kb, vb, ob);
    // o = attn @ Wp + bp -> fp32 tmp
    gemm_k<0><<<32 * 12, 256, 0, stream>>>(ob, tp, bp + (size_t)l * 768,
                                           tmp, nullptr, nullptr, nullptr, 768, 768);
    // r1 = LN2(o) + x
    ln_k<0, 1><<<2048, 256, 0, stream>>>(tmp, g2 + l * 768, be2 + l * 768,
                                         xout, nullptr, r1);
    // h2 = LN3(r1) -> bf16
    ln_k<1, 0><<<2048, 256, 0, stream>>>(r1, g3 + l * 768, be3 + l * 768,
                                         nullptr, nullptr, hb);
    // f1 = gelu(h2 @ W1 + b1) -> bf16
    gemm_k<2><<<32 * 48, 256, 0, stream>>>(hb, t1, b1 + (size_t)l * 3072,
                                           f1b, nullptr, nullptr, nullptr, 3072, 768);
    // f2 = f1 @ W2 + b2 -> fp32 tmp
    gemm_k<0><<<32 * 12, 256, 0, stream>>>(f1b, t2, b2 + (size_t)l * 768,
                                           tmp, nullptr, nullptr, nullptr, 768, 3072);
    // x = x + LN4(f2) + r1   (in-place on d_out)
    ln_k<0, 2><<<2048, 256, 0, stream>>>(tmp, g4 + l * 768, be4 + l * 768,
                                         r1, xout, xout);
  }
}

// Round 2
// 2146.025 us; speedup vs baseline: 1.9751x; 1.9751x over previous
//
#include <hip/hip_runtime.h>
#include <hip/hip_bf16.h>
#include <stdint.h>

// Problem constants: B=4, S=512, E=768, H=12, D=64, L=12, FF=3072, M = B*S = 2048
#define LAYERS 12
#define M_ROWS 2048
#define E_DIM 768
#define FF_DIM 3072
#define QKV_DIM 2304
#define SCALE_INV 0.036084391824351615f  // 1/sqrt(768)

typedef __hip_bfloat16 bf16;
typedef __attribute__((ext_vector_type(8))) __bf16 bf16x8;
typedef __attribute__((ext_vector_type(4))) float f32x4;

__device__ __forceinline__ float bf2f(bf16 v) { return __bfloat162float(v); }
__device__ __forceinline__ bf16 f2bf(float v) { return __float2bfloat16(v); }

__device__ __forceinline__ float gelu_f(float x) {
  return 0.5f * x * (1.0f + erff(x * 0.70710678118654752f));
}

// ---------------------------------------------------------------------------
// Batched weight transpose+convert: fp32 [K][N] -> bf16 [N][K] for the 4
// weight matrices of one layer. 32x32 tiles via LDS.
// ---------------------------------------------------------------------------
__global__ __launch_bounds__(256) void transpose_k(
    const float* __restrict__ w0, const float* __restrict__ w1,
    const float* __restrict__ w2, const float* __restrict__ w3,
    bf16* __restrict__ t0, bf16* __restrict__ t1,
    bf16* __restrict__ t2, bf16* __restrict__ t3)
{
  __shared__ float T[32][33];
  int bid = blockIdx.x;
  const float* src; bf16* dst; int K, N, tile;
  if (bid < 1728)      { src = w0; dst = t0; K = 768;  N = 2304; tile = bid; }
  else if (bid < 2304) { src = w1; dst = t1; K = 768;  N = 768;  tile = bid - 1728; }
  else if (bid < 4608) { src = w2; dst = t2; K = 768;  N = 3072; tile = bid - 2304; }
  else                 { src = w3; dst = t3; K = 3072; N = 768;  tile = bid - 4608; }
  int tilesN = N >> 5;
  int tk = tile / tilesN;
  int tn = tile - tk * tilesN;
  int tx = threadIdx.x & 31, ty = threadIdx.x >> 5;
  int k0 = tk << 5, n0 = tn << 5;
#pragma unroll
  for (int i = 0; i < 4; i++)
    T[ty + i * 8][tx] = src[(size_t)(k0 + ty + i * 8) * N + n0 + tx];
  __syncthreads();
#pragma unroll
  for (int i = 0; i < 4; i++)
    dst[(size_t)(n0 + ty + i * 8) * K + k0 + tx] = f2bf(T[tx][ty + i * 8]);
}

// ---------------------------------------------------------------------------
// LayerNorm over last dim (768). One block (256 thr) per row.
// ---------------------------------------------------------------------------
template<int OUT_BF16, int NADD>
__global__ __launch_bounds__(256) void ln_k(
    const float* in, const float* gamma, const float* beta,
    const float* add0, const float* add1, void* outp)
{
  int row = blockIdx.x, tid = threadIdx.x;
  const float* x = in + (size_t)row * 768;
  float v[3]; float s = 0.f, sq = 0.f;
#pragma unroll
  for (int j = 0; j < 3; j++) {
    v[j] = x[tid + j * 256];
    s += v[j]; sq += v[j] * v[j];
  }
#pragma unroll
  for (int off = 32; off; off >>= 1) {
    s += __shfl_xor(s, off);
    sq += __shfl_xor(sq, off);
  }
  __shared__ float red[8];
  int wv = tid >> 6;
  if ((tid & 63) == 0) { red[wv] = s; red[4 + wv] = sq; }
  __syncthreads();
  s  = red[0] + red[1] + red[2] + red[3];
  sq = red[4] + red[5] + red[6] + red[7];
  float mean = s * (1.0f / 768.0f);
  float var  = sq * (1.0f / 768.0f) - mean * mean;
  float rstd = rsqrtf(var + 1e-5f);
#pragma unroll
  for (int j = 0; j < 3; j++) {
    int c = tid + j * 256;
    float val = (v[j] - mean) * rstd * gamma[c] + beta[c];
    if (NADD >= 1) val += add0[(size_t)row * 768 + c];
    if (NADD >= 2) val += add1[(size_t)row * 768 + c];
    if (OUT_BF16) ((bf16*)outp)[(size_t)row * 768 + c] = f2bf(val);
    else          ((float*)outp)[(size_t)row * 768 + c] = val;
  }
}

// ---------------------------------------------------------------------------
// bf16 MFMA GEMM:  C[M=2048][N] = A[2048][K] @ W[K][N] + bias
// OUT_MODE: 0 = fp32 out, 1 = bf16 out, 2 = bf16+GELU out,
//           3 = split-QKV out; q,k as [B][H][S][D], v TRANSPOSED [B][H][D][S].
// ---------------------------------------------------------------------------
template<int OUT_MODE>
__global__ __launch_bounds__(256) void gemm_k(
    const bf16* __restrict__ A, const bf16* __restrict__ BT,
    const float* __restrict__ bias, void* __restrict__ Cout,
    bf16* __restrict__ qo, bf16* __restrict__ ko, bf16* __restrict__ vo,
    int N, int K)
{
  __shared__ __align__(16) bf16 Als[64 * 32];
  __shared__ __align__(16) bf16 Bls[64 * 32];
  int tid = threadIdx.x;
  int lane = tid & 63, wave = tid >> 6;
  int wm = (wave >> 1) * 32, wn = (wave & 1) * 32;
  int m0 = (blockIdx.x & 31) << 6;
  int n0 = (blockIdx.x >> 5) << 6;
  const bf16* Ap = A + (size_t)m0 * K;
  const bf16* Bp = BT + (size_t)n0 * K;
  int sr = tid >> 2;
  int sc = (tid & 3) * 8;
  f32x4 acc[2][2] = {};
  for (int k0 = 0; k0 < K; k0 += 32) {
    uint4 av = *(const uint4*)(Ap + (size_t)sr * K + k0 + sc);
    uint4 bv = *(const uint4*)(Bp + (size_t)sr * K + k0 + sc);
    __syncthreads();
    *(uint4*)&Als[tid * 8] = av;
    *(uint4*)&Bls[tid * 8] = bv;
    __syncthreads();
    int ko8 = (lane >> 4) * 8;
    bf16x8 af[2], bfr[2];
#pragma unroll
    for (int i = 0; i < 2; i++)
      af[i] = *(const bf16x8*)&Als[(wm + i * 16 + (lane & 15)) * 32 + ko8];
#pragma unroll
    for (int j = 0; j < 2; j++)
      bfr[j] = *(const bf16x8*)&Bls[(wn + j * 16 + (lane & 15)) * 32 + ko8];
#pragma unroll
    for (int i = 0; i < 2; i++)
#pragma unroll
      for (int j = 0; j < 2; j++)
        acc[i][j] = __builtin_amdgcn_mfma_f32_16x16x32_bf16(af[i], bfr[j], acc[i][j], 0, 0, 0);
  }
#pragma unroll
  for (int i = 0; i < 2; i++) {
    int mbase = m0 + wm + i * 16 + ((lane >> 4) << 2);
#pragma unroll
    for (int j = 0; j < 2; j++) {
      int n = n0 + wn + j * 16 + (lane & 15);
      float bvs = bias[n];
      if (OUT_MODE == 3) {
        int h = n / 192;
        int rm = n - h * 192;
        int d = rm / 3;
        int t = rm - d * 3;
#pragma unroll
        for (int rg = 0; rg < 4; rg++) {
          int m = mbase + rg;
          float val = acc[i][j][rg] + bvs;
          int b = m >> 9, sIdx = m & 511;
          int bh = b * 12 + h;
          if (t == 2)
            vo[(size_t)((bh << 6) + d) * 512 + sIdx] = f2bf(val);       // [B][H][D][S]
          else {
            bf16* dsts = (t == 0) ? qo : ko;
            dsts[(size_t)((bh << 9) + sIdx) * 64 + d] = f2bf(val);      // [B][H][S][D]
          }
        }
      } else {
#pragma unroll
        for (int rg = 0; rg < 4; rg++) {
          int m = mbase + rg;
          float val = acc[i][j][rg] + bvs;
          if (OUT_MODE == 0)      ((float*)Cout)[(size_t)m * N + n] = val;
          else if (OUT_MODE == 1) ((bf16*)Cout)[(size_t)m * N + n] = f2bf(val);
          else                    ((bf16*)Cout)[(size_t)m * N + n] = f2bf(gelu_f(val));
        }
      }
    }
  }
}

// ---------------------------------------------------------------------------
// MFMA flash attention. Block = one (b,h) x 64 query rows; 4 waves x 16 rows.
// q,k: bf16 [B][H][S][D];  vT: bf16 [B][H][D][S];  o: bf16 [B*S][768].
// att = softmax(q.k) / sqrt(768)  (scale after softmax — faithful).
// Online softmax over 8 key-tiles of 64.
// ---------------------------------------------------------------------------
#define PSTR 80   // P staging row stride (bf16 elems): 160B rows -> 4-way max conflict
__global__ __launch_bounds__(256) void attn_k(
    const bf16* __restrict__ q, const bf16* __restrict__ k,
    const bf16* __restrict__ vT, bf16* __restrict__ o)
{
  __shared__ __align__(16) bf16 Kls[64 * 64];        // [key][d]
  __shared__ __align__(16) bf16 Vls[64 * 64];        // [d][key]
  __shared__ __align__(16) bf16 Pls[4][16 * PSTR];   // per-wave P transpose buf
  int tid = threadIdx.x;
  int lane = tid & 63, w = tid >> 6;
  int l15 = lane & 15, l4 = lane >> 4;
  int qt = blockIdx.x & 7;
  int bh = blockIdx.x >> 3;
  size_t base = (size_t)bh * 32768;    // 512*64

  // Q A-fragments, loaded once from global (contiguous d)
  const bf16* qrowp = q + base + (size_t)(qt * 64 + w * 16 + l15) * 64 + l4 * 8;
  bf16x8 qf0 = *(const bf16x8*)qrowp;
  bf16x8 qf1 = *(const bf16x8*)(qrowp + 32);

  float mrow[4] = {-1e30f, -1e30f, -1e30f, -1e30f};
  float lsum[4] = {0.f, 0.f, 0.f, 0.f};
  f32x4 Oacc[4] = {};
  const f32x4 zed = {0.f, 0.f, 0.f, 0.f};
  bf16* pw = &Pls[w][0];

  for (int kt = 0; kt < 8; kt++) {
    __syncthreads();   // previous iter's LDS reads done before overwrite
    // stage K tile [64][64] and VT tile [64 d][64 kk]
#pragma unroll
    for (int rep = 0; rep < 2; rep++) {
      int c = tid + rep * 256;
      int row = c >> 3, col8 = (c & 7) * 8;
      *(uint4*)&Kls[row * 64 + col8] =
          *(const uint4*)(k + base + (size_t)(kt * 64 + row) * 64 + col8);
      *(uint4*)&Vls[row * 64 + col8] =
          *(const uint4*)(vT + base + (size_t)row * 512 + kt * 64 + col8);
    }
    __syncthreads();
    // e = Q @ K^T for this wave's 16 rows x 64 keys (4 C-tiles)
    f32x4 e[4];
#pragma unroll
    for (int jt = 0; jt < 4; jt++) {
      bf16x8 kf0 = *(const bf16x8*)&Kls[(jt * 16 + l15) * 64 + l4 * 8];
      bf16x8 kf1 = *(const bf16x8*)&Kls[(jt * 16 + l15) * 64 + l4 * 8 + 32];
      e[jt] = __builtin_amdgcn_mfma_f32_16x16x32_bf16(qf0, kf0, zed, 0, 0, 0);
      e[jt] = __builtin_amdgcn_mfma_f32_16x16x32_bf16(qf1, kf1, e[jt], 0, 0, 0);
    }
    // online softmax stats; row = l4*4+reg, shared by the 16 lanes with same l4
    float al[4];
#pragma unroll
    for (int rg = 0; rg < 4; rg++) {
      float mn = fmaxf(fmaxf(e[0][rg], e[1][rg]), fmaxf(e[2][rg], e[3][rg]));
#pragma unroll
      for (int off = 1; off < 16; off <<= 1) mn = fmaxf(mn, __shfl_xor(mn, off));
      float mnew = fmaxf(mrow[rg], mn);
      al[rg] = __expf(mrow[rg] - mnew);
      mrow[rg] = mnew;
    }
    float rs[4] = {0.f, 0.f, 0.f, 0.f};
#pragma unroll
    for (int jt = 0; jt < 4; jt++)
#pragma unroll
      for (int rg = 0; rg < 4; rg++) {
        float p = __expf(e[jt][rg] - mrow[rg]);
        rs[rg] += p;
        pw[(l4 * 4 + rg) * PSTR + jt * 16 + l15] = f2bf(p);
      }
#pragma unroll
    for (int rg = 0; rg < 4; rg++) {
#pragma unroll
      for (int off = 1; off < 16; off <<= 1) rs[rg] += __shfl_xor(rs[rg], off);
      lsum[rg] = lsum[rg] * al[rg] + rs[rg];
    }
#pragma unroll
    for (int dt = 0; dt < 4; dt++)
#pragma unroll
      for (int rg = 0; rg < 4; rg++) Oacc[dt][rg] *= al[rg];
    // P back out in A-layout (within-wave LDS round trip)
    bf16x8 pf0 = *(const bf16x8*)&pw[l15 * PSTR + l4 * 8];
    bf16x8 pf1 = *(const bf16x8*)&pw[l15 * PSTR + l4 * 8 + 32];
    // O += P @ V  (B-operand from VT: n=d, k=key, contiguous key)
#pragma unroll
    for (int dt = 0; dt < 4; dt++) {
      bf16x8 vf0 = *(const bf16x8*)&Vls[(dt * 16 + l15) * 64 + l4 * 8];
      bf16x8 vf1 = *(const bf16x8*)&Vls[(dt * 16 + l15) * 64 + l4 * 8 + 32];
      Oacc[dt] = __builtin_amdgcn_mfma_f32_16x16x32_bf16(pf0, vf0, Oacc[dt], 0, 0, 0);
      Oacc[dt] = __builtin_amdgcn_mfma_f32_16x16x32_bf16(pf1, vf1, Oacc[dt], 0, 0, 0);
    }
  }
  // epilogue: O[q][d] * SCALE_INV / l  -> o[b*512+s][h*64+d]
  int b = bh / 12, h = bh - b * 12;
#pragma unroll
  for (int rg = 0; rg < 4; rg++) {
    int qrow = qt * 64 + w * 16 + l4 * 4 + rg;
    float inv = SCALE_INV / lsum[rg];
    size_t rowoff = (size_t)(b * 512 + qrow) * 768 + h * 64;
#pragma unroll
    for (int dt = 0; dt < 4; dt++)
      o[rowoff + dt * 16 + l15] = f2bf(Oacc[dt][rg] * inv);
  }
}

// ---------------------------------------------------------------------------
extern "C" void kernel_launch(void* const* d_in, const int* in_sizes, int n_in,
                              void* d_out, int out_size, void* d_ws, size_t ws_size,
                              hipStream_t stream)
{
  const float* x    = (const float*)d_in[0];
  const float* Wqkv = (const float*)d_in[1];
  const float* bqkv = (const float*)d_in[2];
  const float* Wp   = (const float*)d_in[3];
  const float* bp   = (const float*)d_in[4];
  const float* W1   = (const float*)d_in[5];
  const float* b1   = (const float*)d_in[6];
  const float* W2   = (const float*)d_in[7];
  const float* b2   = (const float*)d_in[8];
  const float* g1  = (const float*)d_in[9];
  const float* be1 = (const float*)d_in[10];
  const float* g2  = (const float*)d_in[11];
  const float* be2 = (const float*)d_in[12];
  const float* g3  = (const float*)d_in[13];
  const float* be3 = (const float*)d_in[14];
  const float* g4  = (const float*)d_in[15];
  const float* be4 = (const float*)d_in[16];
  float* xout = (float*)d_out;

  char* ws = (char*)d_ws;
  size_t off = 0;
  auto alloc = [&](size_t bytes) -> char* {
    char* p = ws + off;
    off += (bytes + 255) & ~(size_t)255;
    return p;
  };
  const size_t NTOK = (size_t)M_ROWS * E_DIM;
  bf16*  qb  = (bf16*)alloc(NTOK * 2);
  bf16*  kb  = (bf16*)alloc(NTOK * 2);
  bf16*  vb  = (bf16*)alloc(NTOK * 2);   // holds V^T [B][H][D][S]
  bf16*  hb  = (bf16*)alloc(NTOK * 2);
  bf16*  ob  = (bf16*)alloc(NTOK * 2);
  bf16*  f1b = (bf16*)alloc((size_t)M_ROWS * FF_DIM * 2);
  float* tmp = (float*)alloc(NTOK * 4);
  float* r1  = (float*)alloc(NTOK * 4);
  bf16*  tq  = (bf16*)alloc((size_t)768 * 2304 * 2);
  bf16*  tp  = (bf16*)alloc((size_t)768 * 768 * 2);
  bf16*  t1  = (bf16*)alloc((size_t)768 * 3072 * 2);
  bf16*  t2  = (bf16*)alloc((size_t)3072 * 768 * 2);
  if (off > ws_size) {
    hipMemsetAsync(d_out, 0x7f, (size_t)out_size * 4, stream);
    return;
  }

  hipMemcpyAsync(d_out, x, (size_t)out_size * 4, hipMemcpyDeviceToDevice, stream);

  for (int l = 0; l < LAYERS; l++) {
    const float* wq  = Wqkv + (size_t)l * 768 * 2304;
    const float* wp_ = Wp   + (size_t)l * 768 * 768;
    const float* w1_ = W1   + (size_t)l * 768 * 3072;
    const float* w2_ = W2   + (size_t)l * 3072 * 768;

    transpose_k<<<6912, 256, 0, stream>>>(wq, wp_, w1_, w2_, tq, tp, t1, t2);

    ln_k<1, 0><<<2048, 256, 0, stream>>>(xout, g1 + l * 768, be1 + l * 768,
                                         nullptr, nullptr, hb);
    gemm_k<3><<<32 * 36, 256, 0, stream>>>(hb, tq, bqkv + (size_t)l * 2304,
                                           nullptr, qb, kb, vb, 2304, 768);
    attn_k<<<384, 256, 0, stream>>>(qb, kb, vb, ob);
    gemm_k<0><<<32 * 12, 256, 0, stream>>>(ob, tp, bp + (size_t)l * 768,
                                           tmp, nullptr, nullptr, nullptr, 768, 768);
    ln_k<0, 1><<<2048, 256, 0, stream>>>(tmp, g2 + l * 768, be2 + l * 768,
                                         xout, nullptr, r1);
    ln_k<1, 0><<<2048, 256, 0, stream>>>(r1, g3 + l * 768, be3 + l * 768,
                                         nullptr, nullptr, hb);
    gemm_k<2><<<32 * 48, 256, 0, stream>>>(hb, t1, b1 + (size_t)l * 3072,
                                           f1b, nullptr, nullptr, nullptr, 3072, 768);
    gemm_k<0><<<32 * 12, 256, 0, stream>>>(f1b, t2, b2 + (size_t)l * 768,
                                           tmp, nullptr, nullptr, nullptr, 768, 3072);
    ln_k<0, 2><<<2048, 256, 0, stream>>>(tmp, g4 + l * 768, be4 + l * 768,
                                         r1, xout, xout);
  }
}